// Round 3
// baseline (282.985 us; speedup 1.0000x reference)
//
#include <hip/hip_runtime.h>
#include <hip/hip_bf16.h>

#define E_DIM 128
#define L_DIM 64
#define HDIM 64

__device__ __forceinline__ float waveSum(float v) {
#pragma unroll
  for (int o = 32; o > 0; o >>= 1) v += __shfl_xor(v, o);
  return v;
}
__device__ __forceinline__ float waveMax(float v) {
#pragma unroll
  for (int o = 32; o > 0; o >>= 1) v = fmaxf(v, __shfl_xor(v, o));
  return v;
}

// One block per batch row. Computes the 3 branch features into `feats`
// and per-block score partials into `partials[k*B + b]`.
__global__ __launch_bounds__(256) void phase1(
    const float* __restrict__ user_embs,
    const float* __restrict__ item_embs,
    const float* __restrict__ w_uu,
    const float* __restrict__ w_uiu,
    const float* __restrict__ w_uui,
    const float* __restrict__ W0,
    const float* __restrict__ b0,
    const float* __restrict__ w1,
    const int* __restrict__ uid,
    const int* __restrict__ nbr,
    const int* __restrict__ uiu,
    const int* __restrict__ uui,
    float* __restrict__ feats,     // [3][B][E]
    float* __restrict__ partials,  // [3][B]
    int B) {
  const int b = blockIdx.x;
  const int tid = threadIdx.x;

  __shared__ float s_self[E_DIM];
  __shared__ float s_w[2 * E_DIM];
  __shared__ float s_feat[L_DIM][E_DIM + 1];  // +1 pad: conflict-free dots
  __shared__ float s_a[L_DIM];
  __shared__ int s_mask[L_DIM];
  __shared__ float s_out[E_DIM];

  const int u = uid[b];
  if (tid < E_DIM) s_self[tid] = user_embs[(long)u * E_DIM + tid];
  __syncthreads();

  for (int k = 0; k < 3; ++k) {
    const float* w = (k == 0) ? w_uu : (k == 1) ? w_uiu : w_uui;
    s_w[tid] = w[tid];  // 256 threads == 2*E_DIM elems

    // ---- gather + build feat tile (all 256 threads) ----
    // 128-float row = 32 chunks of float4; 32 lanes/row, 8 rows/pass.
    const int r = tid >> 5;  // 0..7: neighbor row within 8-row batch
    const int c = tid & 31;  // 0..31: float4 chunk within the row
    for (int l0 = 0; l0 < L_DIM; l0 += 8) {
      const int l = l0 + r;
      float f[4];
      int midx;
      if (k == 0) {
        const int i1 = nbr[(long)b * L_DIM + l];
        midx = i1;
        const float4 g = *(const float4*)(user_embs + (long)i1 * E_DIM + c * 4);
        f[0] = (s_self[c * 4 + 0] + g.x) * 0.5f;
        f[1] = (s_self[c * 4 + 1] + g.y) * 0.5f;
        f[2] = (s_self[c * 4 + 2] + g.z) * 0.5f;
        f[3] = (s_self[c * 4 + 3] + g.w) * 0.5f;
      } else {
        const int* mp = (k == 1) ? uiu : uui;
        const int i0 = mp[((long)b * 2 + 0) * L_DIM + l];
        const int i1 = mp[((long)b * 2 + 1) * L_DIM + l];
        midx = i0;  // mask is on the first component in both branches
        const float* t0 = (k == 1) ? item_embs : user_embs;
        const float* t1 = (k == 1) ? user_embs : item_embs;
        const float4 g0 = *(const float4*)(t0 + (long)i0 * E_DIM + c * 4);
        const float4 g1 = *(const float4*)(t1 + (long)i1 * E_DIM + c * 4);
        f[0] = (s_self[c * 4 + 0] + g0.x + g1.x) * (1.0f / 3.0f);
        f[1] = (s_self[c * 4 + 1] + g0.y + g1.y) * (1.0f / 3.0f);
        f[2] = (s_self[c * 4 + 2] + g0.z + g1.z) * (1.0f / 3.0f);
        f[3] = (s_self[c * 4 + 3] + g0.w + g1.w) * (1.0f / 3.0f);
      }
#pragma unroll
      for (int j = 0; j < 4; ++j) s_feat[l][c * 4 + j] = f[j];
      if (c == 0) s_mask[l] = (midx == 0);
    }
    __syncthreads();

    // ---- logits + 64-wide softmax (wave 0 only) ----
    if (tid < L_DIM) {
      const int l = tid;
      float acc = 0.f;
#pragma unroll
      for (int e = 0; e < E_DIM; ++e)
        acc += s_self[e] * s_w[e] + s_feat[l][e] * s_w[E_DIM + e];
      acc = (acc > 0.f) ? acc : 0.01f * acc;  // leaky_relu
      if (s_mask[l]) acc += -100000000.0f;
      const float m = waveMax(acc);
      const float ex = __expf(acc - m);
      const float sum = waveSum(ex);
      s_a[l] = ex / sum;
    }
    __syncthreads();

    // ---- weighted feat sum + relu + store (128 threads) ----
    if (tid < E_DIM) {
      const int e = tid;
      float acc = 0.f;
#pragma unroll
      for (int l = 0; l < L_DIM; ++l) acc += s_a[l] * s_feat[l][e];
      acc = fmaxf(acc, 0.f);
      s_out[e] = acc;
      feats[((long)k * B + b) * E_DIM + e] = acc;
    }
    __syncthreads();

    // ---- inter(): tanh(s_out @ W0 + b0) . w1 -> per-block partial ----
    if (tid < HDIM) {
      const int j = tid;
      float acc = b0[j];
      for (int e = 0; e < E_DIM; ++e) acc += s_out[e] * W0[e * HDIM + j];
      const float p = tanhf(acc) * w1[j];
      const float sum = waveSum(p);
      if (j == 0) partials[(long)k * B + b] = sum;
    }
    __syncthreads();
  }
}

// One block: sum partials[3][B], softmax over the 3 means -> weights[3].
__global__ __launch_bounds__(256) void reduce_scores(
    const float* __restrict__ partials, float* __restrict__ weights, int B) {
  __shared__ float red[256];
  const int tid = threadIdx.x;
  float s[3];
#pragma unroll
  for (int k = 0; k < 3; ++k) {
    float acc = 0.f;
    for (int i = tid; i < B; i += 256) acc += partials[(long)k * B + i];
    red[tid] = acc;
    __syncthreads();
    for (int off = 128; off > 0; off >>= 1) {
      if (tid < off) red[tid] += red[tid + off];
      __syncthreads();
    }
    s[k] = red[0];
    __syncthreads();
  }
  if (tid == 0) {
    const float inv_b = 1.0f / (float)B;
    const float s0 = s[0] * inv_b, s1 = s[1] * inv_b, s2 = s[2] * inv_b;
    const float m = fmaxf(s0, fmaxf(s1, s2));
    const float e0 = __expf(s0 - m);
    const float e1 = __expf(s1 - m);
    const float e2 = __expf(s2 - m);
    const float inv = 1.0f / (e0 + e1 + e2);
    weights[0] = e0 * inv;
    weights[1] = e1 * inv;
    weights[2] = e2 * inv;
  }
}

__global__ __launch_bounds__(256) void phase2(
    const float* __restrict__ feats, const float* __restrict__ weights,
    float* __restrict__ out, int B) {
  const int i = blockIdx.x * blockDim.x + threadIdx.x;
  const int n = B * E_DIM;
  if (i >= n) return;
  const float w0 = weights[0], w1 = weights[1], w2 = weights[2];
  const float v = w0 * feats[i] + w1 * feats[n + i] + w2 * feats[2 * n + i];
  out[i] = fmaxf(v, 0.f);
}

extern "C" void kernel_launch(void* const* d_in, const int* in_sizes, int n_in,
                              void* d_out, int out_size, void* d_ws,
                              size_t ws_size, hipStream_t stream) {
  const float* user_embs = (const float*)d_in[0];
  const float* item_embs = (const float*)d_in[1];
  const float* w_uu = (const float*)d_in[2];
  const float* w_uiu = (const float*)d_in[3];
  const float* w_uui = (const float*)d_in[4];
  const float* W0 = (const float*)d_in[5];
  const float* b0 = (const float*)d_in[6];
  const float* w1 = (const float*)d_in[7];
  const int* uid = (const int*)d_in[8];
  const int* nbr = (const int*)d_in[9];
  const int* uiu = (const int*)d_in[10];
  const int* uui = (const int*)d_in[11];
  const int B = in_sizes[8];

  float* ws = (float*)d_ws;
  float* partials = ws;            // [3][B]
  float* weights = ws + 3 * B;     // [3]
  float* feats = ws + 3 * B + 64;  // [3][B][E]

  phase1<<<B, 256, 0, stream>>>(user_embs, item_embs, w_uu, w_uiu, w_uui, W0,
                                b0, w1, uid, nbr, uiu, uui, feats, partials, B);
  reduce_scores<<<1, 256, 0, stream>>>(partials, weights, B);
  const int n = B * E_DIM;
  phase2<<<(n + 255) / 256, 256, 0, stream>>>(feats, weights, (float*)d_out, B);
}

// Round 4
// 240.137 us; speedup vs baseline: 1.1784x; 1.1784x over previous
//
#include <hip/hip_runtime.h>
#include <hip/hip_bf16.h>

#define E_DIM 128
#define L_DIM 64
#define HDIM 64

__device__ __forceinline__ float waveSum(float v) {
#pragma unroll
  for (int o = 32; o > 0; o >>= 1) v += __shfl_xor(v, o);
  return v;
}

// One wave per (b, k). Online softmax over 64 neighbors; no feat tile,
// no block barriers in the hot loop. Lane = embedding dim pair (e, e+64).
__global__ __launch_bounds__(256) void phase1(
    const float* __restrict__ user_embs,
    const float* __restrict__ item_embs,
    const float* __restrict__ w_uu,
    const float* __restrict__ w_uiu,
    const float* __restrict__ w_uui,
    const float* __restrict__ W0,
    const float* __restrict__ b0,
    const float* __restrict__ w1,
    const int* __restrict__ uid,
    const int* __restrict__ nbr,
    const int* __restrict__ uiu,
    const int* __restrict__ uui,
    float* __restrict__ feats,     // [3][B][E]
    float* __restrict__ partials,  // [3][B]
    int B) {
  const int lane = threadIdx.x & 63;
  const int wv = threadIdx.x >> 6;  // wave within block (0..3)
  const int w_id = blockIdx.x * 4 + wv;
  const int b = w_id / 3;
  const int k = w_id - 3 * b;
  if (b >= B) return;

  __shared__ float sc[4][E_DIM];  // per-wave broadcast scratch for inter()

  // ---- per-wave setup ----
  const int u = uid[b];
  const float self0 = user_embs[u * E_DIM + lane];
  const float self1 = user_embs[u * E_DIM + 64 + lane];

  const float* w = (k == 0) ? w_uu : (k == 1) ? w_uiu : w_uui;
  const float wa0 = w[lane], wa1 = w[64 + lane];
  const float wb0 = w[128 + lane], wb1 = w[192 + lane];
  const float logit_self = waveSum(self0 * wa0 + self1 * wa1);

  const bool is_uu = (k == 0);
  const float scale = is_uu ? 0.5f : (1.0f / 3.0f);
  // tables: k==0 -> user; k==1 (uiu) -> item,user; k==2 (uui) -> user,item
  const float* t0 = (k == 1) ? item_embs : user_embs;
  const float* t1 = (k == 1) ? user_embs : item_embs;

  // lane l holds the indices + mask for neighbor l (coalesced preload)
  int i0_l, i1_l;
  if (is_uu) {
    i0_l = nbr[b * L_DIM + lane];
    i1_l = 0;
  } else {
    const int* mp = (k == 1) ? uiu : uui;
    i0_l = mp[(b * 2 + 0) * L_DIM + lane];
    i1_l = mp[(b * 2 + 1) * L_DIM + lane];
  }
  const float mask_l = (i0_l == 0) ? 1.0f : 0.0f;

  // ---- online-softmax stream over neighbors ----
  float m = -3.0e38f, s = 0.0f, o0 = 0.0f, o1 = 0.0f;

  int i0 = __shfl(i0_l, 0);
  int i1 = __shfl(i1_l, 0);
  float g00 = t0[i0 * E_DIM + lane];
  float g01 = t0[i0 * E_DIM + 64 + lane];
  float g10 = 0.f, g11 = 0.f;
  if (!is_uu) {
    g10 = t1[i1 * E_DIM + lane];
    g11 = t1[i1 * E_DIM + 64 + lane];
  }

  for (int l = 0; l < L_DIM; ++l) {
    const float f0 = (self0 + g00 + g10) * scale;
    const float f1 = (self1 + g01 + g11) * scale;

    // prefetch next neighbor's rows while we reduce this one
    if (l < L_DIM - 1) {
      i0 = __shfl(i0_l, l + 1);
      i1 = __shfl(i1_l, l + 1);
      g00 = t0[i0 * E_DIM + lane];
      g01 = t0[i0 * E_DIM + 64 + lane];
      if (!is_uu) {
        g10 = t1[i1 * E_DIM + lane];
        g11 = t1[i1 * E_DIM + 64 + lane];
      }
    }

    float logit = waveSum(f0 * wb0 + f1 * wb1) + logit_self;
    logit = (logit > 0.f) ? logit : 0.01f * logit;       // leaky_relu
    logit += -100000000.0f * __shfl(mask_l, l);          // mask

    const float mn = fmaxf(m, logit);
    const float alpha = __expf(m - mn);                  // 0 on first iter
    const float p = __expf(logit - mn);
    s = s * alpha + p;
    o0 = o0 * alpha + p * f0;
    o1 = o1 * alpha + p * f1;
    m = mn;
  }

  const float inv_s = 1.0f / s;
  const float r0 = fmaxf(o0 * inv_s, 0.f);
  const float r1 = fmaxf(o1 * inv_s, 0.f);
  feats[((long)k * B + b) * E_DIM + lane] = r0;
  feats[((long)k * B + b) * E_DIM + 64 + lane] = r1;

  // ---- inter(): hid[j] = b0[j] + sum_e r[e] * W0[e][j], j = lane ----
  sc[wv][lane] = r0;
  sc[wv][64 + lane] = r1;
  __syncthreads();  // uniform path; aligns the 4 independent waves, cheap

  float hid = b0[lane];
#pragma unroll 4
  for (int e = 0; e < E_DIM; ++e)
    hid += sc[wv][e] * W0[e * HDIM + lane];  // sc: broadcast; W0: L1-hot
  const float p = tanhf(hid) * w1[lane];
  const float sum = waveSum(p);
  if (lane == 0) partials[(long)k * B + b] = sum;
}

// One block: sum partials[3][B], softmax over the 3 means -> weights[3].
__global__ __launch_bounds__(256) void reduce_scores(
    const float* __restrict__ partials, float* __restrict__ weights, int B) {
  __shared__ float red[256];
  const int tid = threadIdx.x;
  float s[3];
#pragma unroll
  for (int k = 0; k < 3; ++k) {
    float acc = 0.f;
    for (int i = tid; i < B; i += 256) acc += partials[(long)k * B + i];
    red[tid] = acc;
    __syncthreads();
    for (int off = 128; off > 0; off >>= 1) {
      if (tid < off) red[tid] += red[tid + off];
      __syncthreads();
    }
    s[k] = red[0];
    __syncthreads();
  }
  if (tid == 0) {
    const float inv_b = 1.0f / (float)B;
    const float s0 = s[0] * inv_b, s1 = s[1] * inv_b, s2 = s[2] * inv_b;
    const float m = fmaxf(s0, fmaxf(s1, s2));
    const float e0 = __expf(s0 - m);
    const float e1 = __expf(s1 - m);
    const float e2 = __expf(s2 - m);
    const float inv = 1.0f / (e0 + e1 + e2);
    weights[0] = e0 * inv;
    weights[1] = e1 * inv;
    weights[2] = e2 * inv;
  }
}

__global__ __launch_bounds__(256) void phase2(
    const float* __restrict__ feats, const float* __restrict__ weights,
    float* __restrict__ out, int B) {
  const int i = blockIdx.x * blockDim.x + threadIdx.x;
  const int n = B * E_DIM;
  if (i >= n) return;
  const float w0 = weights[0], w1 = weights[1], w2 = weights[2];
  const float v = w0 * feats[i] + w1 * feats[n + i] + w2 * feats[2 * n + i];
  out[i] = fmaxf(v, 0.f);
}

extern "C" void kernel_launch(void* const* d_in, const int* in_sizes, int n_in,
                              void* d_out, int out_size, void* d_ws,
                              size_t ws_size, hipStream_t stream) {
  const float* user_embs = (const float*)d_in[0];
  const float* item_embs = (const float*)d_in[1];
  const float* w_uu = (const float*)d_in[2];
  const float* w_uiu = (const float*)d_in[3];
  const float* w_uui = (const float*)d_in[4];
  const float* W0 = (const float*)d_in[5];
  const float* b0 = (const float*)d_in[6];
  const float* w1 = (const float*)d_in[7];
  const int* uid = (const int*)d_in[8];
  const int* nbr = (const int*)d_in[9];
  const int* uiu = (const int*)d_in[10];
  const int* uui = (const int*)d_in[11];
  const int B = in_sizes[8];

  float* ws = (float*)d_ws;
  float* partials = ws;            // [3][B]
  float* weights = ws + 3 * B;     // [3]
  float* feats = ws + 3 * B + 64;  // [3][B][E]

  const int n_waves = 3 * B;
  const int n_blocks = (n_waves + 3) / 4;  // 4 waves per 256-thread block
  phase1<<<n_blocks, 256, 0, stream>>>(user_embs, item_embs, w_uu, w_uiu,
                                       w_uui, W0, b0, w1, uid, nbr, uiu, uui,
                                       feats, partials, B);
  reduce_scores<<<1, 256, 0, stream>>>(partials, weights, B);
  const int n = B * E_DIM;
  phase2<<<(n + 255) / 256, 256, 0, stream>>>(feats, weights, (float*)d_out, B);
}